// Round 5
// baseline (425.463 us; speedup 1.0000x reference)
//
#include <hip/hip_runtime.h>

#define H 4096
#define THREADS 256
#define ROWS 4
#define CHUNKS 4   // H / (THREADS * 4)

__device__ __forceinline__ float dot4(float4 a, float4 b) {
    return a.x * b.x + a.y * b.y + a.z * b.z + a.w * b.w;
}

// Pack two f32 into one u32 of bf16s (round-to-nearest-even).
__device__ __forceinline__ unsigned pack_bf16(float a, float b) {
    unsigned ua = __float_as_uint(a), ub = __float_as_uint(b);
    ua = (ua + 0x7FFFu + ((ua >> 16) & 1u)) >> 16;
    ub = (ub + 0x7FFFu + ((ub >> 16) & 1u)) >> 16;
    return ua | (ub << 16);
}
__device__ __forceinline__ float unpack_lo(unsigned p) { return __uint_as_float(p << 16); }
__device__ __forceinline__ float unpack_hi(unsigned p) { return __uint_as_float(p & 0xFFFF0000u); }

// ---------- kernel 0: C[rp][r] = sum_d A_v[rp][d] * B_q[d][r]  (4x4) ----------
__global__ void __launch_bounds__(THREADS) compute_C_kernel(
    const float* __restrict__ A_v, const float* __restrict__ B_q,
    float* __restrict__ C)
{
    const int tid = threadIdx.x;
    float acc[4][4];
#pragma unroll
    for (int i = 0; i < 4; ++i)
#pragma unroll
        for (int j = 0; j < 4; ++j) acc[i][j] = 0.f;

#pragma unroll
    for (int c = 0; c < CHUNKS; ++c) {
        const int d0 = c * (THREADS * 4) + tid * 4;
        float avf[4][4], bqf[4][4];
#pragma unroll
        for (int r = 0; r < 4; ++r) {
            float4 t = *reinterpret_cast<const float4*>(A_v + (size_t)r * H + d0);
            avf[r][0] = t.x; avf[r][1] = t.y; avf[r][2] = t.z; avf[r][3] = t.w;
        }
#pragma unroll
        for (int i = 0; i < 4; ++i) {
            float4 t = *reinterpret_cast<const float4*>(B_q + (size_t)(d0 + i) * 4);
            bqf[i][0] = t.x; bqf[i][1] = t.y; bqf[i][2] = t.z; bqf[i][3] = t.w;
        }
#pragma unroll
        for (int i = 0; i < 4; ++i)
#pragma unroll
            for (int rp = 0; rp < 4; ++rp)
#pragma unroll
                for (int r = 0; r < 4; ++r)
                    acc[rp][r] += avf[rp][i] * bqf[i][r];
    }

    const int lane = tid & 63, wave = tid >> 6;
    __shared__ float red[4][16];
#pragma unroll
    for (int rp = 0; rp < 4; ++rp)
#pragma unroll
        for (int r = 0; r < 4; ++r) {
            float v = acc[rp][r];
#pragma unroll
            for (int off = 32; off; off >>= 1) v += __shfl_down(v, off, 64);
            if (lane == 0) red[wave][rp * 4 + r] = v;
        }
    __syncthreads();
    if (tid < 16) C[tid] = red[0][tid] + red[1][tid] + red[2][tid] + red[3][tid];
}

// ---------- fused kernel: R0 dataflow, bf16-packed x staging ----------
// x read ONCE; dots computed from fresh f32 values; staged copy is bf16
// (32 VGPR instead of 64) so we land in a higher occupancy tier.
__global__ void __launch_bounds__(THREADS, 6) lora_fused_kernel(
    const float* __restrict__ x,
    const float* __restrict__ A_q, const float* __restrict__ B_q,
    const float* __restrict__ A_v, const float* __restrict__ B_v,
    const float* __restrict__ C,
    float* __restrict__ out)
{
    const int tid = threadIdx.x;
    const size_t row0 = (size_t)blockIdx.x * ROWS;
    const float* xbase = x + row0 * H;

    unsigned xp[ROWS][CHUNKS][2];       // 32 VGPR: bf16-packed x staging
    float accq[ROWS][4], accv[ROWS][4];
#pragma unroll
    for (int m = 0; m < ROWS; ++m)
#pragma unroll
        for (int r = 0; r < 4; ++r) { accq[m][r] = 0.f; accv[m][r] = 0.f; }

    // ---- Phase 1: rank-4 projections (f32 dots; bf16 pack for keeping) ----
#pragma unroll
    for (int c = 0; c < CHUNKS; ++c) {
        const int d0 = c * (THREADS * 4) + tid * 4;
        float4 xv[ROWS];
#pragma unroll
        for (int m = 0; m < ROWS; ++m) {
            xv[m] = *reinterpret_cast<const float4*>(xbase + (size_t)m * H + d0);
            xp[m][c][0] = pack_bf16(xv[m].x, xv[m].y);
            xp[m][c][1] = pack_bf16(xv[m].z, xv[m].w);
        }
#pragma unroll
        for (int r = 0; r < 4; ++r) {
            float4 aq = *reinterpret_cast<const float4*>(A_q + (size_t)r * H + d0);
#pragma unroll
            for (int m = 0; m < ROWS; ++m) accq[m][r] += dot4(xv[m], aq);
        }
#pragma unroll
        for (int r = 0; r < 4; ++r) {
            float4 av = *reinterpret_cast<const float4*>(A_v + (size_t)r * H + d0);
#pragma unroll
            for (int m = 0; m < ROWS; ++m) accv[m][r] += dot4(xv[m], av);
        }
    }

    // ---- Block reduction: 32 values (idx = m*8 + v; v<4 accq, v>=4 accv) ----
    const int lane = tid & 63, wave = tid >> 6;
    __shared__ float red[4][32];
    __shared__ float sums[32];
#pragma unroll
    for (int i = 0; i < 32; ++i) {
        const int m = i >> 3, v = i & 7;
        float s = (v < 4) ? accq[m][v] : accv[m][v - 4];
#pragma unroll
        for (int off = 1; off < 64; off <<= 1) s += __shfl_xor(s, off, 64);
        if (lane == 0) red[wave][i] = s;
    }
    __syncthreads();
    if (tid < 32) sums[tid] = red[0][tid] + red[1][tid] + red[2][tid] + red[3][tid];
    __syncthreads();

    // Per-thread: lq2 = 2*lq, lv2 = 2*(lowx_v + 2*lq.C^T)  (scaling folded in)
    float lq2[ROWS][4], lv2[ROWS][4];
    {
        float cm[16];
#pragma unroll
        for (int i = 0; i < 16; ++i) cm[i] = C[i];
#pragma unroll
        for (int m = 0; m < ROWS; ++m) {
#pragma unroll
            for (int r = 0; r < 4; ++r) lq2[m][r] = 2.f * sums[m * 8 + r];
#pragma unroll
            for (int rp = 0; rp < 4; ++rp) {
                float s = sums[m * 8 + 4 + rp];
#pragma unroll
                for (int r = 0; r < 4; ++r) s += sums[m * 8 + r] * 2.f * cm[rp * 4 + r];
                lv2[m][rp] = 2.f * s;
            }
        }
    }

    // ---- Phase 2: out = 2*x + lq2.Bq[d] + lv2.Bv[d]  (x from bf16 regs) ----
#pragma unroll
    for (int c = 0; c < CHUNKS; ++c) {
        const int d0 = c * (THREADS * 4) + tid * 4;
        float o[ROWS][4];
#pragma unroll
        for (int i = 0; i < 4; ++i) {
            float4 bq = *reinterpret_cast<const float4*>(B_q + (size_t)(d0 + i) * 4);
            float4 bv = *reinterpret_cast<const float4*>(B_v + (size_t)(d0 + i) * 4);
#pragma unroll
            for (int m = 0; m < ROWS; ++m) {
                const unsigned p = xp[m][c][i >> 1];
                const float xs = (i & 1) ? unpack_hi(p) : unpack_lo(p);
                float dq = lq2[m][0] * bq.x + lq2[m][1] * bq.y + lq2[m][2] * bq.z + lq2[m][3] * bq.w;
                float dv = lv2[m][0] * bv.x + lv2[m][1] * bv.y + lv2[m][2] * bv.z + lv2[m][3] * bv.w;
                o[m][i] = 2.f * xs + dq + dv;
            }
        }
#pragma unroll
        for (int m = 0; m < ROWS; ++m) {
            float4 ov = make_float4(o[m][0], o[m][1], o[m][2], o[m][3]);
            *reinterpret_cast<float4*>(out + (row0 + m) * H + d0) = ov;
        }
    }
}

extern "C" void kernel_launch(void* const* d_in, const int* in_sizes, int n_in,
                              void* d_out, int out_size, void* d_ws, size_t ws_size,
                              hipStream_t stream) {
    const float* x   = (const float*)d_in[0];
    const float* A_q = (const float*)d_in[1];
    const float* B_q = (const float*)d_in[2];
    const float* A_v = (const float*)d_in[3];
    const float* B_v = (const float*)d_in[4];
    float* out = (float*)d_out;
    float* C   = (float*)d_ws;          // 16 floats

    const int nrows = in_sizes[0] / H;  // B*S = 8192

    compute_C_kernel<<<1, THREADS, 0, stream>>>(A_v, B_q, C);
    lora_fused_kernel<<<nrows / ROWS, THREADS, 0, stream>>>(
        x, A_q, B_q, A_v, B_v, C, out);
}

// Round 6
// 94.097 us; speedup vs baseline: 4.5215x; 4.5215x over previous
//
#include <hip/hip_runtime.h>

#define H 4096
#define THREADS 256
#define ROWS 2
#define CHUNKS 4   // H / (THREADS * 4)

__device__ __forceinline__ float dot4(float4 a, float4 b) {
    return a.x * b.x + a.y * b.y + a.z * b.z + a.w * b.w;
}

// Pack two f32 into one u32 of bf16s (round-to-nearest-even).
__device__ __forceinline__ unsigned pack_bf16(float a, float b) {
    unsigned ua = __float_as_uint(a), ub = __float_as_uint(b);
    ua = (ua + 0x7FFFu + ((ua >> 16) & 1u)) >> 16;
    ub = (ub + 0x7FFFu + ((ub >> 16) & 1u)) >> 16;
    return ua | (ub << 16);
}
__device__ __forceinline__ float unpack_lo(unsigned p) { return __uint_as_float(p << 16); }
__device__ __forceinline__ float unpack_hi(unsigned p) { return __uint_as_float(p & 0xFFFF0000u); }

// ---------- kernel 0: C[rp][r] = sum_d A_v[rp][d] * B_q[d][r]  (4x4) ----------
__global__ void __launch_bounds__(THREADS) compute_C_kernel(
    const float* __restrict__ A_v, const float* __restrict__ B_q,
    float* __restrict__ C)
{
    const int tid = threadIdx.x;
    float acc[4][4];
#pragma unroll
    for (int i = 0; i < 4; ++i)
#pragma unroll
        for (int j = 0; j < 4; ++j) acc[i][j] = 0.f;

#pragma unroll
    for (int c = 0; c < CHUNKS; ++c) {
        const int d0 = c * (THREADS * 4) + tid * 4;
        float avf[4][4], bqf[4][4];
#pragma unroll
        for (int r = 0; r < 4; ++r) {
            float4 t = *reinterpret_cast<const float4*>(A_v + (size_t)r * H + d0);
            avf[r][0] = t.x; avf[r][1] = t.y; avf[r][2] = t.z; avf[r][3] = t.w;
        }
#pragma unroll
        for (int i = 0; i < 4; ++i) {
            float4 t = *reinterpret_cast<const float4*>(B_q + (size_t)(d0 + i) * 4);
            bqf[i][0] = t.x; bqf[i][1] = t.y; bqf[i][2] = t.z; bqf[i][3] = t.w;
        }
#pragma unroll
        for (int i = 0; i < 4; ++i)
#pragma unroll
            for (int rp = 0; rp < 4; ++rp)
#pragma unroll
                for (int r = 0; r < 4; ++r)
                    acc[rp][r] += avf[rp][i] * bqf[i][r];
    }

    const int lane = tid & 63, wave = tid >> 6;
    __shared__ float red[4][16];
#pragma unroll
    for (int rp = 0; rp < 4; ++rp)
#pragma unroll
        for (int r = 0; r < 4; ++r) {
            float v = acc[rp][r];
#pragma unroll
            for (int off = 32; off; off >>= 1) v += __shfl_down(v, off, 64);
            if (lane == 0) red[wave][rp * 4 + r] = v;
        }
    __syncthreads();
    if (tid < 16) C[tid] = red[0][tid] + red[1][tid] + red[2][tid] + red[3][tid];
}

// ---------- fused kernel: single-pass dataflow, VGPR <= 64 honestly ----------
// ROWS=2 + bf16-packed x staging (16 VGPR). NO min-waves launch bound:
// forced caps in R1-R4 made the allocator spill arrays to scratch
// (WRITE_SIZE 688 MB vs 134 MB of real output). Let it allocate freely.
__global__ void __launch_bounds__(THREADS) lora_fused_kernel(
    const float* __restrict__ x,
    const float* __restrict__ A_q, const float* __restrict__ B_q,
    const float* __restrict__ A_v, const float* __restrict__ B_v,
    const float* __restrict__ C,
    float* __restrict__ out)
{
    const int tid = threadIdx.x;
    const size_t row0 = (size_t)blockIdx.x * ROWS;
    const float* xbase = x + row0 * H;

    unsigned xp[ROWS][CHUNKS][2];       // 16 VGPR: bf16-packed x staging
    float accq[ROWS][4], accv[ROWS][4]; // 16 VGPR
#pragma unroll
    for (int m = 0; m < ROWS; ++m)
#pragma unroll
        for (int r = 0; r < 4; ++r) { accq[m][r] = 0.f; accv[m][r] = 0.f; }

    // ---- Phase 1: rank-4 projections (f32 dots; bf16 pack for keeping) ----
#pragma unroll
    for (int c = 0; c < CHUNKS; ++c) {
        const int d0 = c * (THREADS * 4) + tid * 4;
        float4 xv[ROWS];
#pragma unroll
        for (int m = 0; m < ROWS; ++m) {
            xv[m] = *reinterpret_cast<const float4*>(xbase + (size_t)m * H + d0);
            xp[m][c][0] = pack_bf16(xv[m].x, xv[m].y);
            xp[m][c][1] = pack_bf16(xv[m].z, xv[m].w);
        }
#pragma unroll
        for (int r = 0; r < 4; ++r) {
            float4 aq = *reinterpret_cast<const float4*>(A_q + (size_t)r * H + d0);
#pragma unroll
            for (int m = 0; m < ROWS; ++m) accq[m][r] += dot4(xv[m], aq);
        }
#pragma unroll
        for (int r = 0; r < 4; ++r) {
            float4 av = *reinterpret_cast<const float4*>(A_v + (size_t)r * H + d0);
#pragma unroll
            for (int m = 0; m < ROWS; ++m) accv[m][r] += dot4(xv[m], av);
        }
    }

    // ---- Block reduction: 16 values (idx = m*8 + v; v<4 accq, v>=4 accv) ----
    const int lane = tid & 63, wave = tid >> 6;
    __shared__ float red[4][16];
    __shared__ float sums[16];
#pragma unroll
    for (int i = 0; i < 16; ++i) {
        const int m = i >> 3, v = i & 7;
        float s = (v < 4) ? accq[m][v] : accv[m][v - 4];
#pragma unroll
        for (int off = 1; off < 64; off <<= 1) s += __shfl_xor(s, off, 64);
        if (lane == 0) red[wave][i] = s;
    }
    __syncthreads();
    if (tid < 16) sums[tid] = red[0][tid] + red[1][tid] + red[2][tid] + red[3][tid];
    __syncthreads();

    // Per-thread: lq2 = 2*lq, lv2 = 2*(lowx_v + 2*lq.C^T)  (scaling folded in)
    float lq2[ROWS][4], lv2[ROWS][4];
    {
        float cm[16];
#pragma unroll
        for (int i = 0; i < 16; ++i) cm[i] = C[i];
#pragma unroll
        for (int m = 0; m < ROWS; ++m) {
#pragma unroll
            for (int r = 0; r < 4; ++r) lq2[m][r] = 2.f * sums[m * 8 + r];
#pragma unroll
            for (int rp = 0; rp < 4; ++rp) {
                float s = sums[m * 8 + 4 + rp];
#pragma unroll
                for (int r = 0; r < 4; ++r) s += sums[m * 8 + r] * 2.f * cm[rp * 4 + r];
                lv2[m][rp] = 2.f * s;
            }
        }
    }

    // ---- Phase 2: out = 2*x + lq2.Bq[d] + lv2.Bv[d]  (x from bf16 regs) ----
#pragma unroll
    for (int c = 0; c < CHUNKS; ++c) {
        const int d0 = c * (THREADS * 4) + tid * 4;
        float o[ROWS][4];
#pragma unroll
        for (int i = 0; i < 4; ++i) {
            float4 bq = *reinterpret_cast<const float4*>(B_q + (size_t)(d0 + i) * 4);
            float4 bv = *reinterpret_cast<const float4*>(B_v + (size_t)(d0 + i) * 4);
#pragma unroll
            for (int m = 0; m < ROWS; ++m) {
                const unsigned p = xp[m][c][i >> 1];
                const float xs = (i & 1) ? unpack_hi(p) : unpack_lo(p);
                float dq = lq2[m][0] * bq.x + lq2[m][1] * bq.y + lq2[m][2] * bq.z + lq2[m][3] * bq.w;
                float dv = lv2[m][0] * bv.x + lv2[m][1] * bv.y + lv2[m][2] * bv.z + lv2[m][3] * bv.w;
                o[m][i] = 2.f * xs + dq + dv;
            }
        }
#pragma unroll
        for (int m = 0; m < ROWS; ++m) {
            float4 ov = make_float4(o[m][0], o[m][1], o[m][2], o[m][3]);
            *reinterpret_cast<float4*>(out + (row0 + m) * H + d0) = ov;
        }
    }
}

extern "C" void kernel_launch(void* const* d_in, const int* in_sizes, int n_in,
                              void* d_out, int out_size, void* d_ws, size_t ws_size,
                              hipStream_t stream) {
    const float* x   = (const float*)d_in[0];
    const float* A_q = (const float*)d_in[1];
    const float* B_q = (const float*)d_in[2];
    const float* A_v = (const float*)d_in[3];
    const float* B_v = (const float*)d_in[4];
    float* out = (float*)d_out;
    float* C   = (float*)d_ws;          // 16 floats

    const int nrows = in_sizes[0] / H;  // B*S = 8192

    compute_C_kernel<<<1, THREADS, 0, stream>>>(A_v, B_q, C);
    lora_fused_kernel<<<nrows / ROWS, THREADS, 0, stream>>>(
        x, A_q, B_q, A_v, B_v, C, out);
}